// Round 12
// baseline (197.455 us; speedup 1.0000x reference)
//
#include <hip/hip_runtime.h>
#include <hip/hip_fp16.h>

#define HID 64
#define POS_DIM 32
#define IN_DIM 128

using short8 = __attribute__((ext_vector_type(8))) short;
using f32x4  = __attribute__((ext_vector_type(4))) float;

__device__ __forceinline__ float fsig(float v) {
    return 1.0f / (1.0f + __expf(-v));
}

// round-to-nearest-even fp32 -> bf16 bits
__device__ __forceinline__ unsigned short f2bf(float f) {
    unsigned int u = __float_as_uint(f);
    u = u + 0x7FFFu + ((u >> 16) & 1u);
    return (unsigned short)(u >> 16);
}
__device__ __forceinline__ float bf2f(unsigned short s) {
    return __uint_as_float(((unsigned int)s) << 16);
}
__device__ __forceinline__ float2 bfpair(unsigned int u) {
    return make_float2(__uint_as_float(u << 16),
                       __uint_as_float(u & 0xFFFF0000u));
}
__device__ __forceinline__ unsigned int pack2bf(float a, float b) {
    return (unsigned int)f2bf(a) | ((unsigned int)f2bf(b) << 16);
}
// fp16 pair pack/unpack for CSR coefficients
__device__ __forceinline__ int pack2h(float a, float b) {
    __half2 h2 = __floats2half2_rn(a, b);
    return *reinterpret_cast<int*>(&h2);
}
__device__ __forceinline__ float cextract(int bits, int layer) {
    __half2 h2 = *reinterpret_cast<__half2*>(&bits);
    return layer ? __half2float(__high2half(h2)) : __half2float(__low2half(h2));
}

// ---------------- pos -> bf16 copy (L2-resident gather operand) ----------------
__global__ __launch_bounds__(256) void k_posbf(const float* __restrict__ pos,
                                               unsigned int* __restrict__ posh,
                                               int total2) {   // total2 = N*POS_DIM/2
    int i = blockIdx.x * blockDim.x + threadIdx.x;
    if (i >= total2) return;
    float2 v = ((const float2*)pos)[i];
    posh[i] = pack2bf(v.x, v.y);
}

// ---------------- in-degree histogram ----------------
__global__ __launch_bounds__(256) void k_hist(const int* __restrict__ tp,
                                              int* cnt, int E) {
    int i = blockIdx.x * blockDim.x + threadIdx.x;
    if (i < E) atomicAdd(&cnt[tp[E + i]], 1);   // col = tp[1][i]
}

// ---------------- scan phase 1 ----------------
__global__ __launch_bounds__(256) void k_bsum(const int* __restrict__ cnt,
                                              int* __restrict__ bsum, int n) {
    int i = blockIdx.x * 256 + threadIdx.x;
    int v = (i < n) ? cnt[i] : 0;
    #pragma unroll
    for (int o = 32; o; o >>= 1) v += __shfl_down(v, o);
    __shared__ int w[4];
    int lane = threadIdx.x & 63, wid = threadIdx.x >> 6;
    if (lane == 0) w[wid] = v;
    __syncthreads();
    if (threadIdx.x == 0) bsum[blockIdx.x] = w[0] + w[1] + w[2] + w[3];
}

// ---------------- scan phase 2: off, cursor copy, dinv ----------------
__global__ __launch_bounds__(256) void k_scan2(const int* __restrict__ cnt,
                                               const int* __restrict__ bsum,
                                               int* __restrict__ off,
                                               int* __restrict__ cur,
                                               float* __restrict__ dinv,
                                               int n, int Etot) {
    __shared__ int s[256];
    __shared__ int wsum[4];
    int tid = threadIdx.x, bid = blockIdx.x;
    int p = 0;
    for (int t = tid; t < bid; t += 256) p += bsum[t];
    #pragma unroll
    for (int o = 32; o; o >>= 1) p += __shfl_down(p, o);
    int lane = tid & 63, wid = tid >> 6;
    if (lane == 0) wsum[wid] = p;
    __syncthreads();
    int bpre = wsum[0] + wsum[1] + wsum[2] + wsum[3];
    int i = bid * 256 + tid;
    int v = (i < n) ? cnt[i] : 0;
    s[tid] = v;
    __syncthreads();
    #pragma unroll
    for (int d = 1; d < 256; d <<= 1) {
        int t_ = (tid >= d) ? s[tid - d] : 0;
        __syncthreads();
        s[tid] += t_;
        __syncthreads();
    }
    if (i < n) {
        int ov = bpre + s[tid] - v;
        off[i]  = ov;
        cur[i]  = ov;
        dinv[i] = rsqrtf((float)(v + 1));
    }
    if (i == 0) off[n] = Etot;
}

// ---------------- fused sqdist + coef + CSR scatter ----------------
// 8 lanes per edge (uint2 of bf16-pos each), 2 edges per group, 2-lane tail split.
__global__ __launch_bounds__(256) void k_fill2(const int* __restrict__ tp,
                                               const unsigned int* __restrict__ posh,
                                               const float* __restrict__ dinv,
                                               int* cur,
                                               const float* em1w, const float* em1b,
                                               const float* em2w, const float* em2b,
                                               int2* __restrict__ csr, int E) {
    int lane = threadIdx.x & 63;
    int wid  = threadIdx.x >> 6;
    int sub  = lane >> 3;                  // group 0..7
    int j    = lane & 7;
    int base = (blockIdx.x * 4 + wid) * 16;
    int e0 = base + sub;
    int e1 = base + 8 + sub;
    if (e0 >= E) return;
    bool v1 = (e1 < E);
    int row0 = tp[e0],            col0 = tp[E + e0];
    int row1 = v1 ? tp[e1] : 0;
    int col1 = v1 ? tp[E + e1] : 0;
    const uint2* ph = (const uint2*)posh;   // row = 8 uint2 (64 B)
    uint2 a0 = ph[(size_t)row0 * 8 + j];
    uint2 b0 = ph[(size_t)col0 * 8 + j];
    uint2 a1 = ph[(size_t)row1 * 8 + j];
    uint2 b1 = ph[(size_t)col1 * 8 + j];
    float s0, s1;
    {
        float2 ax = bfpair(a0.x), ay = bfpair(a0.y);
        float2 bx = bfpair(b0.x), by = bfpair(b0.y);
        float d0 = ax.x - bx.x, d1 = ax.y - bx.y;
        float d2 = ay.x - by.x, d3 = ay.y - by.y;
        s0 = d0 * d0;
        s0 = fmaf(d1, d1, s0); s0 = fmaf(d2, d2, s0); s0 = fmaf(d3, d3, s0);
    }
    {
        float2 ax = bfpair(a1.x), ay = bfpair(a1.y);
        float2 bx = bfpair(b1.x), by = bfpair(b1.y);
        float d0 = ax.x - bx.x, d1 = ax.y - bx.y;
        float d2 = ay.x - by.x, d3 = ay.y - by.y;
        s1 = d0 * d0;
        s1 = fmaf(d1, d1, s1); s1 = fmaf(d2, d2, s1); s1 = fmaf(d3, d3, s1);
    }
    s0 += __shfl_xor(s0, 1);  s1 += __shfl_xor(s1, 1);
    s0 += __shfl_xor(s0, 2);  s1 += __shfl_xor(s1, 2);
    s0 += __shfl_xor(s0, 4);  s1 += __shfl_xor(s1, 4);
    // both sums now in all 8 lanes: lane 0 finishes e0, lane 1 finishes e1
    if (j < 2) {
        bool valid = j ? v1 : true;
        if (valid) {
            int   rr = j ? row1 : row0;
            int   cc = j ? col1 : col0;
            float ss = j ? s1   : s0;
            float nrm = dinv[rr] * dinv[cc];
            float c1 = fsig(ss * em1w[0] + em1b[0]) * nrm;
            float c2 = fsig(ss * em2w[0] + em2b[0]) * nrm;
            int slot = atomicAdd(&cur[cc], 1);
            csr[slot] = make_int2(rr, pack2h(c1, c2));
        }
    }
}

// ---------------- MFMA GEMM: H[n,64] = X[n,K] @ W[K,64], bf16 out ----------------
template<int K, bool IN_BF16>
__global__ __launch_bounds__(256) void k_gemm_mfma(const void* __restrict__ Xv,
                                                   const float* __restrict__ W,
                                                   unsigned short* __restrict__ H,
                                                   int n) {
    constexpr int RB   = K * 2;        // row bytes
    constexpr int CPR  = K / 8;        // 16B chunks per row
    __shared__ unsigned char lds[64 * RB * 2];
    unsigned char* As = lds;
    unsigned char* Bt = lds + 64 * RB;

    int tid  = threadIdx.x;
    int row0 = blockIdx.x * 64;

    for (int i = tid; i < 64 * CPR; i += 256) {
        int r  = i / CPR;
        int kb = i % CPR;
        uint4 val;
        if (row0 + r < n) {
            if (IN_BF16) {
                val = *(const uint4*)((const unsigned short*)Xv + (size_t)(row0 + r) * K + kb * 8);
            } else {
                const float* src = (const float*)Xv + (size_t)(row0 + r) * K + kb * 8;
                float4 f0 = ((const float4*)src)[0];
                float4 f1 = ((const float4*)src)[1];
                val.x = pack2bf(f0.x, f0.y); val.y = pack2bf(f0.z, f0.w);
                val.z = pack2bf(f1.x, f1.y); val.w = pack2bf(f1.z, f1.w);
            }
        } else {
            val = make_uint4(0, 0, 0, 0);
        }
        *(uint4*)(As + r * RB + ((kb ^ (r & 7)) << 4)) = val;
    }
    for (int i = tid; i < K * 16; i += 256) {
        int k  = i / 16;
        int c0 = (i % 16) * 4;
        float4 w = ((const float4*)W)[i];
        #pragma unroll
        for (int u = 0; u < 4; ++u) {
            int c = c0 + u;
            float vv = (u == 0) ? w.x : (u == 1) ? w.y : (u == 2) ? w.z : w.w;
            int byte = c * RB + ((((k * 2) >> 4) ^ (c & 7)) << 4) + ((k & 7) * 2);
            *(unsigned short*)(Bt + byte) = f2bf(vv);
        }
    }
    __syncthreads();

    int wv   = tid >> 6;
    int lane = tid & 63;
    int l15  = lane & 15;
    int g    = lane >> 4;

    f32x4 acc[4] = {{0,0,0,0},{0,0,0,0},{0,0,0,0},{0,0,0,0}};
    #pragma unroll
    for (int kk = 0; kk < K / 32; ++kk) {
        int kc = kk * 4 + g;
        int arow = wv * 16 + l15;
        short8 a = *(const short8*)(As + arow * RB + ((kc ^ (arow & 7)) << 4));
        #pragma unroll
        for (int cb = 0; cb < 4; ++cb) {
            int c = cb * 16 + l15;
            short8 b = *(const short8*)(Bt + c * RB + ((kc ^ (c & 7)) << 4));
            acc[cb] = __builtin_amdgcn_mfma_f32_16x16x32_bf16(a, b, acc[cb], 0, 0, 0);
        }
    }

    #pragma unroll
    for (int cb = 0; cb < 4; ++cb) {
        #pragma unroll
        for (int r = 0; r < 4; ++r) {
            int row = row0 + wv * 16 + g * 4 + r;
            if (row < n) H[(size_t)row * HID + cb * 16 + l15] = f2bf(acc[cb][r]);
        }
    }
}

// ---------------- gather-aggregate: uint-per-lane, 8 edges in flight per wave ----
__global__ __launch_bounds__(256) void k_agg(const int* __restrict__ off,
                                             const int2* __restrict__ csr,
                                             const unsigned short* __restrict__ h,
                                             const float* __restrict__ dinv,
                                             const float* __restrict__ bias,
                                             const float* emb,
                                             unsigned short* __restrict__ out,
                                             int n, int layer) {
    int wid  = threadIdx.x >> 6;
    int lane = threadIdx.x & 63;
    int half = lane >> 5;
    int q    = lane & 31;
    int i = blockIdx.x * 4 + wid;
    if (i >= n) return;
    float accx = 0.0f, accy = 0.0f;
    if (half == 0) {
        float di = dinv[i];
        float sc = fsig(emb[0]) * di * di;
        float2 bv = ((const float2*)bias)[q];
        float2 hv = bfpair(((const unsigned int*)(h + (size_t)i * HID))[q]);
        accx = fmaf(sc, hv.x, bv.x);
        accy = fmaf(sc, hv.y, bv.y);
    }
    int s  = off[i] + half;
    int s1 = off[i + 1];
    for (; s + 6 < s1; s += 8) {
        int2 ea = csr[s],     eb = csr[s + 2];
        int2 ec = csr[s + 4], ed = csr[s + 6];
        float ca = cextract(ea.y, layer);
        float cb = cextract(eb.y, layer);
        float cc = cextract(ec.y, layer);
        float cd = cextract(ed.y, layer);
        float2 va = bfpair(((const unsigned int*)(h + (size_t)ea.x * HID))[q]);
        float2 vb = bfpair(((const unsigned int*)(h + (size_t)eb.x * HID))[q]);
        float2 vc = bfpair(((const unsigned int*)(h + (size_t)ec.x * HID))[q]);
        float2 vd = bfpair(((const unsigned int*)(h + (size_t)ed.x * HID))[q]);
        accx = fmaf(ca, va.x, accx); accy = fmaf(ca, va.y, accy);
        accx = fmaf(cb, vb.x, accx); accy = fmaf(cb, vb.y, accy);
        accx = fmaf(cc, vc.x, accx); accy = fmaf(cc, vc.y, accy);
        accx = fmaf(cd, vd.x, accx); accy = fmaf(cd, vd.y, accy);
    }
    for (; s < s1; s += 2) {
        int2 ea = csr[s];
        float ca = cextract(ea.y, layer);
        float2 va = bfpair(((const unsigned int*)(h + (size_t)ea.x * HID))[q]);
        accx = fmaf(ca, va.x, accx); accy = fmaf(ca, va.y, accy);
    }
    accx += __shfl_down(accx, 32);
    accy += __shfl_down(accy, 32);
    if (half == 0)
        ((unsigned int*)out)[(size_t)i * (HID / 2) + q] = pack2bf(accx, accy);
}

// ---------------- final link predictor: 8 lanes per edge, bf16 h ----------------
__global__ __launch_bounds__(256) void k_predict(const int* __restrict__ pei,
                                                 const int* __restrict__ nei,
                                                 const unsigned short* __restrict__ h,
                                                 const float* __restrict__ pos,
                                                 const float* fcw, const float* fcb,
                                                 float* __restrict__ out, int Elp) {
    int j = threadIdx.x & 7;
    int e = blockIdx.x * 32 + (threadIdx.x >> 3);
    if (e >= 2 * Elp) return;
    int src, dst;
    if (e < Elp) { src = pei[e];        dst = pei[Elp + e]; }
    else         { src = nei[e - Elp];  dst = nei[e];       }
    uint4 hs = ((const uint4*)(h + (size_t)src * HID))[j];
    uint4 hd = ((const uint4*)(h + (size_t)dst * HID))[j];
    float p = 0.0f;
    {
        float2 a, b;
        a = bfpair(hs.x); b = bfpair(hd.x);
        p = fmaf(a.x, b.x, p); p = fmaf(a.y, b.y, p);
        a = bfpair(hs.y); b = bfpair(hd.y);
        p = fmaf(a.x, b.x, p); p = fmaf(a.y, b.y, p);
        a = bfpair(hs.z); b = bfpair(hd.z);
        p = fmaf(a.x, b.x, p); p = fmaf(a.y, b.y, p);
        a = bfpair(hs.w); b = bfpair(hd.w);
        p = fmaf(a.x, b.x, p); p = fmaf(a.y, b.y, p);
    }
    float4 pa = ((const float4*)(pos + (size_t)src * POS_DIM))[j];
    float4 pb = ((const float4*)(pos + (size_t)dst * POS_DIM))[j];
    float dx = pa.x - pb.x, dy = pa.y - pb.y, dz = pa.z - pb.z, dw = pa.w - pb.w;
    float pe = 0.0f;
    pe = fmaf(dx, dx, pe); pe = fmaf(dy, dy, pe);
    pe = fmaf(dz, dz, pe); pe = fmaf(dw, dw, pe);
    p  += __shfl_xor(p, 1);  pe += __shfl_xor(pe, 1);
    p  += __shfl_xor(p, 2);  pe += __shfl_xor(pe, 2);
    p  += __shfl_xor(p, 4);  pe += __shfl_xor(pe, 4);
    if (j == 0) out[e] = fcw[0] * p + fcw[1] * pe + fcb[0];
}

static inline size_t align16(size_t v) { return (v + 15) & ~(size_t)15; }

extern "C" void kernel_launch(void* const* d_in, const int* in_sizes, int n_in,
                              void* d_out, int out_size, void* d_ws, size_t ws_size,
                              hipStream_t stream) {
    const float* x    = (const float*)d_in[0];
    const float* pos  = (const float*)d_in[1];
    const int*   pei  = (const int*)d_in[2];
    const int*   nei  = (const int*)d_in[3];
    const int*   tp   = (const int*)d_in[4];
    const float* W1   = (const float*)d_in[5];
    const float* b1   = (const float*)d_in[6];
    const float* em1w = (const float*)d_in[7];
    const float* em1b = (const float*)d_in[8];
    const float* W2   = (const float*)d_in[9];
    const float* b2   = (const float*)d_in[10];
    const float* em2w = (const float*)d_in[11];
    const float* em2b = (const float*)d_in[12];
    const float* fcw  = (const float*)d_in[13];
    const float* fcb  = (const float*)d_in[14];
    float* outp = (float*)d_out;

    const int N   = in_sizes[0] / IN_DIM;   // 50000
    const int E   = in_sizes[4] / 2;        // 800000
    const int Elp = in_sizes[2] / 2;        // 100000
    const int NB  = (N + 255) / 256;

    char* base = (char*)d_ws;
    size_t o = 0;
    int2* csr = (int2*)(base + o);                        o += align16((size_t)E * 8);
    int*   cnt  = (int*)(base + o);                       o += align16((size_t)N * 4);
    int*   off  = (int*)(base + o);                       o += align16((size_t)(N + 1) * 4);
    int*   cur  = (int*)(base + o);                       o += align16((size_t)N * 4);
    int*   bsum = (int*)(base + o);                       o += align16((size_t)NB * 4);
    float* dinv = (float*)(base + o);                     o += align16((size_t)N * 4);
    unsigned int* posh = (unsigned int*)(base + o);       o += align16((size_t)N * POS_DIM * 2);
    unsigned short* hbuf = (unsigned short*)(base + o);   o += align16((size_t)N * HID * 2);
    unsigned short* obuf = (unsigned short*)(base + o);   o += align16((size_t)N * HID * 2);

    // ---- CSR build ----
    hipMemsetAsync(cnt, 0, (size_t)N * 4, stream);
    k_posbf<<<(N * POS_DIM / 2 + 255) / 256, 256, 0, stream>>>(pos, posh, N * POS_DIM / 2);
    k_hist<<<(E + 255) / 256, 256, 0, stream>>>(tp, cnt, E);
    k_bsum<<<NB, 256, 0, stream>>>(cnt, bsum, N);
    k_scan2<<<NB, 256, 0, stream>>>(cnt, bsum, off, cur, dinv, N, E);
    k_fill2<<<(E + 63) / 64, 256, 0, stream>>>(tp, posh, dinv, cur,
                                               em1w, em1b, em2w, em2b, csr, E);

    // ---- layer 1 ----
    k_gemm_mfma<IN_DIM, false><<<(N + 63) / 64, 256, 0, stream>>>(x, W1, hbuf, N);
    k_agg<<<(N + 3) / 4, 256, 0, stream>>>(off, csr, hbuf, dinv, b1, em1b, obuf, N, 0);

    // ---- layer 2 ----
    k_gemm_mfma<HID, true><<<(N + 63) / 64, 256, 0, stream>>>(obuf, W2, hbuf, N);
    k_agg<<<(N + 3) / 4, 256, 0, stream>>>(off, csr, hbuf, dinv, b2, em2b, obuf, N, 1);

    // ---- predictor: layer-2 output is bf16 in obuf ----
    k_predict<<<(2 * Elp + 31) / 32, 256, 0, stream>>>(pei, nei, obuf,
                                                       pos, fcw, fcb, outp, Elp);
}

// Round 13
// 189.160 us; speedup vs baseline: 1.0439x; 1.0439x over previous
//
#include <hip/hip_runtime.h>
#include <hip/hip_fp16.h>

#define HID 64
#define POS_DIM 32
#define IN_DIM 128

using short8 = __attribute__((ext_vector_type(8))) short;
using f32x4  = __attribute__((ext_vector_type(4))) float;

__device__ __forceinline__ float fsig(float v) {
    return 1.0f / (1.0f + __expf(-v));
}

// round-to-nearest-even fp32 -> bf16 bits
__device__ __forceinline__ unsigned short f2bf(float f) {
    unsigned int u = __float_as_uint(f);
    u = u + 0x7FFFu + ((u >> 16) & 1u);
    return (unsigned short)(u >> 16);
}
__device__ __forceinline__ float bf2f(unsigned short s) {
    return __uint_as_float(((unsigned int)s) << 16);
}
__device__ __forceinline__ float2 bfpair(unsigned int u) {
    return make_float2(__uint_as_float(u << 16),
                       __uint_as_float(u & 0xFFFF0000u));
}
__device__ __forceinline__ unsigned int pack2bf(float a, float b) {
    return (unsigned int)f2bf(a) | ((unsigned int)f2bf(b) << 16);
}
// fp16 pair pack/unpack for CSR coefficients
__device__ __forceinline__ int pack2h(float a, float b) {
    __half2 h2 = __floats2half2_rn(a, b);
    return *reinterpret_cast<int*>(&h2);
}
__device__ __forceinline__ float cextract(int bits, int layer) {
    __half2 h2 = *reinterpret_cast<__half2*>(&bits);
    return layer ? __half2float(__high2half(h2)) : __half2float(__low2half(h2));
}

// ---------------- fused: pos->bf16 copy + in-degree histogram ----------------
// NOTE: total2 = N*POS_DIM/2 == E for this shape; grid covers max of both.
__global__ __launch_bounds__(256) void k_prep(const float* __restrict__ pos,
                                              unsigned int* __restrict__ posh,
                                              const int* __restrict__ tp,
                                              int* cnt, int total2, int E) {
    int i = blockIdx.x * blockDim.x + threadIdx.x;
    if (i < total2) {
        float2 v = ((const float2*)pos)[i];
        posh[i] = pack2bf(v.x, v.y);
    }
    if (i < E) atomicAdd(&cnt[tp[E + i]], 1);   // col = tp[1][i]
}

// ---------------- scan phase 1 ----------------
__global__ __launch_bounds__(256) void k_bsum(const int* __restrict__ cnt,
                                              int* __restrict__ bsum, int n) {
    int i = blockIdx.x * 256 + threadIdx.x;
    int v = (i < n) ? cnt[i] : 0;
    #pragma unroll
    for (int o = 32; o; o >>= 1) v += __shfl_down(v, o);
    __shared__ int w[4];
    int lane = threadIdx.x & 63, wid = threadIdx.x >> 6;
    if (lane == 0) w[wid] = v;
    __syncthreads();
    if (threadIdx.x == 0) bsum[blockIdx.x] = w[0] + w[1] + w[2] + w[3];
}

// ---------------- scan phase 2: off, cursor copy, dinv ----------------
__global__ __launch_bounds__(256) void k_scan2(const int* __restrict__ cnt,
                                               const int* __restrict__ bsum,
                                               int* __restrict__ off,
                                               int* __restrict__ cur,
                                               float* __restrict__ dinv,
                                               int n, int Etot) {
    __shared__ int s[256];
    __shared__ int wsum[4];
    int tid = threadIdx.x, bid = blockIdx.x;
    int p = 0;
    for (int t = tid; t < bid; t += 256) p += bsum[t];
    #pragma unroll
    for (int o = 32; o; o >>= 1) p += __shfl_down(p, o);
    int lane = tid & 63, wid = tid >> 6;
    if (lane == 0) wsum[wid] = p;
    __syncthreads();
    int bpre = wsum[0] + wsum[1] + wsum[2] + wsum[3];
    int i = bid * 256 + tid;
    int v = (i < n) ? cnt[i] : 0;
    s[tid] = v;
    __syncthreads();
    #pragma unroll
    for (int d = 1; d < 256; d <<= 1) {
        int t_ = (tid >= d) ? s[tid - d] : 0;
        __syncthreads();
        s[tid] += t_;
        __syncthreads();
    }
    if (i < n) {
        int ov = bpre + s[tid] - v;
        off[i]  = ov;
        cur[i]  = ov;
        dinv[i] = rsqrtf((float)(v + 1));
    }
    if (i == 0) off[n] = Etot;
}

// ---------------- fused sqdist + coef + CSR scatter ----------------
// 8 lanes per edge (uint2 of bf16-pos each), 2 edges per group, 2-lane tail split.
__global__ __launch_bounds__(256) void k_fill2(const int* __restrict__ tp,
                                               const unsigned int* __restrict__ posh,
                                               const float* __restrict__ dinv,
                                               int* cur,
                                               const float* em1w, const float* em1b,
                                               const float* em2w, const float* em2b,
                                               int2* __restrict__ csr, int E) {
    int lane = threadIdx.x & 63;
    int wid  = threadIdx.x >> 6;
    int sub  = lane >> 3;                  // group 0..7
    int j    = lane & 7;
    int base = (blockIdx.x * 4 + wid) * 16;
    int e0 = base + sub;
    int e1 = base + 8 + sub;
    if (e0 >= E) return;
    bool v1 = (e1 < E);
    int row0 = tp[e0],            col0 = tp[E + e0];
    int row1 = v1 ? tp[e1] : 0;
    int col1 = v1 ? tp[E + e1] : 0;
    const uint2* ph = (const uint2*)posh;   // row = 8 uint2 (64 B)
    uint2 a0 = ph[(size_t)row0 * 8 + j];
    uint2 b0 = ph[(size_t)col0 * 8 + j];
    uint2 a1 = ph[(size_t)row1 * 8 + j];
    uint2 b1 = ph[(size_t)col1 * 8 + j];
    float s0, s1;
    {
        float2 ax = bfpair(a0.x), ay = bfpair(a0.y);
        float2 bx = bfpair(b0.x), by = bfpair(b0.y);
        float d0 = ax.x - bx.x, d1 = ax.y - bx.y;
        float d2 = ay.x - by.x, d3 = ay.y - by.y;
        s0 = d0 * d0;
        s0 = fmaf(d1, d1, s0); s0 = fmaf(d2, d2, s0); s0 = fmaf(d3, d3, s0);
    }
    {
        float2 ax = bfpair(a1.x), ay = bfpair(a1.y);
        float2 bx = bfpair(b1.x), by = bfpair(b1.y);
        float d0 = ax.x - bx.x, d1 = ax.y - bx.y;
        float d2 = ay.x - by.x, d3 = ay.y - by.y;
        s1 = d0 * d0;
        s1 = fmaf(d1, d1, s1); s1 = fmaf(d2, d2, s1); s1 = fmaf(d3, d3, s1);
    }
    s0 += __shfl_xor(s0, 1);  s1 += __shfl_xor(s1, 1);
    s0 += __shfl_xor(s0, 2);  s1 += __shfl_xor(s1, 2);
    s0 += __shfl_xor(s0, 4);  s1 += __shfl_xor(s1, 4);
    if (j < 2) {
        bool valid = j ? v1 : true;
        if (valid) {
            int   rr = j ? row1 : row0;
            int   cc = j ? col1 : col0;
            float ss = j ? s1   : s0;
            float nrm = dinv[rr] * dinv[cc];
            float c1 = fsig(ss * em1w[0] + em1b[0]) * nrm;
            float c2 = fsig(ss * em2w[0] + em2b[0]) * nrm;
            int slot = atomicAdd(&cur[cc], 1);
            csr[slot] = make_int2(rr, pack2h(c1, c2));
        }
    }
}

// ---------------- MFMA GEMM: H[n,64] = X[n,K] @ W[K,64], bf16 out ----------------
template<int K, bool IN_BF16>
__global__ __launch_bounds__(256) void k_gemm_mfma(const void* __restrict__ Xv,
                                                   const float* __restrict__ W,
                                                   unsigned short* __restrict__ H,
                                                   int n) {
    constexpr int RB   = K * 2;        // row bytes
    constexpr int CPR  = K / 8;        // 16B chunks per row
    __shared__ unsigned char lds[64 * RB * 2];
    unsigned char* As = lds;
    unsigned char* Bt = lds + 64 * RB;

    int tid  = threadIdx.x;
    int row0 = blockIdx.x * 64;

    for (int i = tid; i < 64 * CPR; i += 256) {
        int r  = i / CPR;
        int kb = i % CPR;
        uint4 val;
        if (row0 + r < n) {
            if (IN_BF16) {
                val = *(const uint4*)((const unsigned short*)Xv + (size_t)(row0 + r) * K + kb * 8);
            } else {
                const float* src = (const float*)Xv + (size_t)(row0 + r) * K + kb * 8;
                float4 f0 = ((const float4*)src)[0];
                float4 f1 = ((const float4*)src)[1];
                val.x = pack2bf(f0.x, f0.y); val.y = pack2bf(f0.z, f0.w);
                val.z = pack2bf(f1.x, f1.y); val.w = pack2bf(f1.z, f1.w);
            }
        } else {
            val = make_uint4(0, 0, 0, 0);
        }
        *(uint4*)(As + r * RB + ((kb ^ (r & 7)) << 4)) = val;
    }
    for (int i = tid; i < K * 16; i += 256) {
        int k  = i / 16;
        int c0 = (i % 16) * 4;
        float4 w = ((const float4*)W)[i];
        #pragma unroll
        for (int u = 0; u < 4; ++u) {
            int c = c0 + u;
            float vv = (u == 0) ? w.x : (u == 1) ? w.y : (u == 2) ? w.z : w.w;
            int byte = c * RB + ((((k * 2) >> 4) ^ (c & 7)) << 4) + ((k & 7) * 2);
            *(unsigned short*)(Bt + byte) = f2bf(vv);
        }
    }
    __syncthreads();

    int wv   = tid >> 6;
    int lane = tid & 63;
    int l15  = lane & 15;
    int g    = lane >> 4;

    f32x4 acc[4] = {{0,0,0,0},{0,0,0,0},{0,0,0,0},{0,0,0,0}};
    #pragma unroll
    for (int kk = 0; kk < K / 32; ++kk) {
        int kc = kk * 4 + g;
        int arow = wv * 16 + l15;
        short8 a = *(const short8*)(As + arow * RB + ((kc ^ (arow & 7)) << 4));
        #pragma unroll
        for (int cb = 0; cb < 4; ++cb) {
            int c = cb * 16 + l15;
            short8 b = *(const short8*)(Bt + c * RB + ((kc ^ (c & 7)) << 4));
            acc[cb] = __builtin_amdgcn_mfma_f32_16x16x32_bf16(a, b, acc[cb], 0, 0, 0);
        }
    }

    #pragma unroll
    for (int cb = 0; cb < 4; ++cb) {
        #pragma unroll
        for (int r = 0; r < 4; ++r) {
            int row = row0 + wv * 16 + g * 4 + r;
            if (row < n) H[(size_t)row * HID + cb * 16 + l15] = f2bf(acc[cb][r]);
        }
    }
}

// ---------------- gather-aggregate: quarter-wave, 16 rows in flight per wave ----
// wave owns node i; quarter q (16 lanes) takes slots s+q stride 4;
// lane t of a quarter covers cols 4t..4t+3 via one uint2 (row = 128 B).
__global__ __launch_bounds__(256) void k_agg(const int* __restrict__ off,
                                             const int2* __restrict__ csr,
                                             const unsigned short* __restrict__ h,
                                             const float* __restrict__ dinv,
                                             const float* __restrict__ bias,
                                             const float* emb,
                                             unsigned short* __restrict__ out,
                                             int n, int layer) {
    int wid  = threadIdx.x >> 6;
    int lane = threadIdx.x & 63;
    int q    = lane >> 4;                  // quarter 0..3
    int t    = lane & 15;                  // col chunk: cols 4t..4t+3
    int i = blockIdx.x * 4 + wid;
    if (i >= n) return;
    const uint2* hrow = (const uint2*)h;   // row = 16 uint2
    float4 acc = make_float4(0.f, 0.f, 0.f, 0.f);
    if (q == 0) {
        float di = dinv[i];
        float sc = fsig(emb[0]) * di * di;
        float4 bv = ((const float4*)bias)[t];
        uint2 hv = hrow[(size_t)i * 16 + t];
        float2 h0 = bfpair(hv.x), h1 = bfpair(hv.y);
        acc.x = fmaf(sc, h0.x, bv.x);
        acc.y = fmaf(sc, h0.y, bv.y);
        acc.z = fmaf(sc, h1.x, bv.z);
        acc.w = fmaf(sc, h1.y, bv.w);
    }
    int s0 = off[i], s1 = off[i + 1];
    int s = s0;
    // chunks of 16 slots: quarter q handles s+q, s+q+4, s+q+8, s+q+12
    for (; s + 15 < s1; s += 16) {
        int2 ea = csr[s + q];
        int2 eb = csr[s + q + 4];
        int2 ec = csr[s + q + 8];
        int2 ed = csr[s + q + 12];
        float ca = cextract(ea.y, layer);
        float cb = cextract(eb.y, layer);
        float cc = cextract(ec.y, layer);
        float cd = cextract(ed.y, layer);
        uint2 va = hrow[(size_t)ea.x * 16 + t];
        uint2 vb = hrow[(size_t)eb.x * 16 + t];
        uint2 vc = hrow[(size_t)ec.x * 16 + t];
        uint2 vd = hrow[(size_t)ed.x * 16 + t];
        float2 p0, p1;
        p0 = bfpair(va.x); p1 = bfpair(va.y);
        acc.x = fmaf(ca, p0.x, acc.x); acc.y = fmaf(ca, p0.y, acc.y);
        acc.z = fmaf(ca, p1.x, acc.z); acc.w = fmaf(ca, p1.y, acc.w);
        p0 = bfpair(vb.x); p1 = bfpair(vb.y);
        acc.x = fmaf(cb, p0.x, acc.x); acc.y = fmaf(cb, p0.y, acc.y);
        acc.z = fmaf(cb, p1.x, acc.z); acc.w = fmaf(cb, p1.y, acc.w);
        p0 = bfpair(vc.x); p1 = bfpair(vc.y);
        acc.x = fmaf(cc, p0.x, acc.x); acc.y = fmaf(cc, p0.y, acc.y);
        acc.z = fmaf(cc, p1.x, acc.z); acc.w = fmaf(cc, p1.y, acc.w);
        p0 = bfpair(vd.x); p1 = bfpair(vd.y);
        acc.x = fmaf(cd, p0.x, acc.x); acc.y = fmaf(cd, p0.y, acc.y);
        acc.z = fmaf(cd, p1.x, acc.z); acc.w = fmaf(cd, p1.y, acc.w);
    }
    // tail: per-quarter stride 4
    for (int u = s + q; u < s1; u += 4) {
        int2 ea = csr[u];
        float ca = cextract(ea.y, layer);
        uint2 va = hrow[(size_t)ea.x * 16 + t];
        float2 p0 = bfpair(va.x), p1 = bfpair(va.y);
        acc.x = fmaf(ca, p0.x, acc.x); acc.y = fmaf(ca, p0.y, acc.y);
        acc.z = fmaf(ca, p1.x, acc.z); acc.w = fmaf(ca, p1.y, acc.w);
    }
    // merge quarters (lane t identical cols across quarters)
    acc.x += __shfl_xor(acc.x, 16); acc.y += __shfl_xor(acc.y, 16);
    acc.z += __shfl_xor(acc.z, 16); acc.w += __shfl_xor(acc.w, 16);
    acc.x += __shfl_xor(acc.x, 32); acc.y += __shfl_xor(acc.y, 32);
    acc.z += __shfl_xor(acc.z, 32); acc.w += __shfl_xor(acc.w, 32);
    if (q == 0) {
        uint2 o;
        o.x = pack2bf(acc.x, acc.y);
        o.y = pack2bf(acc.z, acc.w);
        ((uint2*)out)[(size_t)i * 16 + t] = o;
    }
}

// ---------------- final link predictor: 8 lanes per edge, bf16 h ----------------
__global__ __launch_bounds__(256) void k_predict(const int* __restrict__ pei,
                                                 const int* __restrict__ nei,
                                                 const unsigned short* __restrict__ h,
                                                 const float* __restrict__ pos,
                                                 const float* fcw, const float* fcb,
                                                 float* __restrict__ out, int Elp) {
    int j = threadIdx.x & 7;
    int e = blockIdx.x * 32 + (threadIdx.x >> 3);
    if (e >= 2 * Elp) return;
    int src, dst;
    if (e < Elp) { src = pei[e];        dst = pei[Elp + e]; }
    else         { src = nei[e - Elp];  dst = nei[e];       }
    uint4 hs = ((const uint4*)(h + (size_t)src * HID))[j];
    uint4 hd = ((const uint4*)(h + (size_t)dst * HID))[j];
    float p = 0.0f;
    {
        float2 a, b;
        a = bfpair(hs.x); b = bfpair(hd.x);
        p = fmaf(a.x, b.x, p); p = fmaf(a.y, b.y, p);
        a = bfpair(hs.y); b = bfpair(hd.y);
        p = fmaf(a.x, b.x, p); p = fmaf(a.y, b.y, p);
        a = bfpair(hs.z); b = bfpair(hd.z);
        p = fmaf(a.x, b.x, p); p = fmaf(a.y, b.y, p);
        a = bfpair(hs.w); b = bfpair(hd.w);
        p = fmaf(a.x, b.x, p); p = fmaf(a.y, b.y, p);
    }
    float4 pa = ((const float4*)(pos + (size_t)src * POS_DIM))[j];
    float4 pb = ((const float4*)(pos + (size_t)dst * POS_DIM))[j];
    float dx = pa.x - pb.x, dy = pa.y - pb.y, dz = pa.z - pb.z, dw = pa.w - pb.w;
    float pe = 0.0f;
    pe = fmaf(dx, dx, pe); pe = fmaf(dy, dy, pe);
    pe = fmaf(dz, dz, pe); pe = fmaf(dw, dw, pe);
    p  += __shfl_xor(p, 1);  pe += __shfl_xor(pe, 1);
    p  += __shfl_xor(p, 2);  pe += __shfl_xor(pe, 2);
    p  += __shfl_xor(p, 4);  pe += __shfl_xor(pe, 4);
    if (j == 0) out[e] = fcw[0] * p + fcw[1] * pe + fcb[0];
}

static inline size_t align16(size_t v) { return (v + 15) & ~(size_t)15; }

extern "C" void kernel_launch(void* const* d_in, const int* in_sizes, int n_in,
                              void* d_out, int out_size, void* d_ws, size_t ws_size,
                              hipStream_t stream) {
    const float* x    = (const float*)d_in[0];
    const float* pos  = (const float*)d_in[1];
    const int*   pei  = (const int*)d_in[2];
    const int*   nei  = (const int*)d_in[3];
    const int*   tp   = (const int*)d_in[4];
    const float* W1   = (const float*)d_in[5];
    const float* b1   = (const float*)d_in[6];
    const float* em1w = (const float*)d_in[7];
    const float* em1b = (const float*)d_in[8];
    const float* W2   = (const float*)d_in[9];
    const float* b2   = (const float*)d_in[10];
    const float* em2w = (const float*)d_in[11];
    const float* em2b = (const float*)d_in[12];
    const float* fcw  = (const float*)d_in[13];
    const float* fcb  = (const float*)d_in[14];
    float* outp = (float*)d_out;

    const int N   = in_sizes[0] / IN_DIM;   // 50000
    const int E   = in_sizes[4] / 2;        // 800000
    const int Elp = in_sizes[2] / 2;        // 100000
    const int NB  = (N + 255) / 256;

    char* base = (char*)d_ws;
    size_t o = 0;
    int2* csr = (int2*)(base + o);                        o += align16((size_t)E * 8);
    int*   cnt  = (int*)(base + o);                       o += align16((size_t)N * 4);
    int*   off  = (int*)(base + o);                       o += align16((size_t)(N + 1) * 4);
    int*   cur  = (int*)(base + o);                       o += align16((size_t)N * 4);
    int*   bsum = (int*)(base + o);                       o += align16((size_t)NB * 4);
    float* dinv = (float*)(base + o);                     o += align16((size_t)N * 4);
    unsigned int* posh = (unsigned int*)(base + o);       o += align16((size_t)N * POS_DIM * 2);
    unsigned short* hbuf = (unsigned short*)(base + o);   o += align16((size_t)N * HID * 2);
    unsigned short* obuf = (unsigned short*)(base + o);   o += align16((size_t)N * HID * 2);

    const int total2 = N * POS_DIM / 2;
    const int prepN  = (total2 > E ? total2 : E);

    // ---- CSR build ----
    hipMemsetAsync(cnt, 0, (size_t)N * 4, stream);
    k_prep<<<(prepN + 255) / 256, 256, 0, stream>>>(pos, posh, tp, cnt, total2, E);
    k_bsum<<<NB, 256, 0, stream>>>(cnt, bsum, N);
    k_scan2<<<NB, 256, 0, stream>>>(cnt, bsum, off, cur, dinv, N, E);
    k_fill2<<<(E + 63) / 64, 256, 0, stream>>>(tp, posh, dinv, cur,
                                               em1w, em1b, em2w, em2b, csr, E);

    // ---- layer 1 ----
    k_gemm_mfma<IN_DIM, false><<<(N + 63) / 64, 256, 0, stream>>>(x, W1, hbuf, N);
    k_agg<<<(N + 3) / 4, 256, 0, stream>>>(off, csr, hbuf, dinv, b1, em1b, obuf, N, 0);

    // ---- layer 2 ----
    k_gemm_mfma<HID, true><<<(N + 63) / 64, 256, 0, stream>>>(obuf, W2, hbuf, N);
    k_agg<<<(N + 3) / 4, 256, 0, stream>>>(off, csr, hbuf, dinv, b2, em2b, obuf, N, 1);

    // ---- predictor: layer-2 output is bf16 in obuf ----
    k_predict<<<(2 * Elp + 31) / 32, 256, 0, stream>>>(pei, nei, obuf,
                                                       pos, fcw, fcb, outp, Elp);
}